// Round 4
// baseline (218.184 us; speedup 1.0000x reference)
//
#include <hip/hip_runtime.h>
#include <math.h>

#define N_VOX 32768
#define N_EMB 8192
#define DIM 64
#define NCHUNK 4
#define CODES_PER_CHUNK (N_EMB / NCHUNK)      // 2048
#define TILES_PER_CHUNK (CODES_PER_CHUNK / 32) // 64
#define NTILES (N_EMB / 32)                   // 256
#define TILE_BYTES (4096 + 4096 + 128)        // eh frags | el' frags | cc0[32]
#define CHUNK_BYTES (TILES_PER_CHUNK * TILE_BYTES)

typedef _Float16 half8 __attribute__((ext_vector_type(8)));
typedef float floatx16 __attribute__((ext_vector_type(16)));

#define FP16_MIN_NORMAL 6.1035156e-5f
#define LO_SCALE 2048.0f

// Split fp32 -> f16 hi (unscaled) + f16 lo = (x - hi)*2048. hi forced to 0 if
// subnormal so lo captures it exactly (dodges MFMA input-denorm ambiguity).
__device__ inline void split8(const float* __restrict__ p, half8& h, half8& l) {
    #pragma unroll
    for (int j = 0; j < 8; ++j) {
        float x  = p[j];
        _Float16 hi = (_Float16)x;
        float hf = (float)hi;
        if (fabsf(hf) < FP16_MIN_NORMAL) { hi = (_Float16)0.f; hf = 0.f; }
        h[j] = hi;
        l[j] = (_Float16)((x - hf) * LO_SCALE);
    }
}

// -------- kernel A: codebook squared norms (validated R1-R3) --------
__global__ __launch_bounds__(256) void esq_kernel(const float* __restrict__ cb,
                                                  float* __restrict__ esq) {
    int gid  = blockIdx.x * blockDim.x + threadIdx.x;
    int code = gid >> 6;
    int lane = threadIdx.x & 63;
    float v = cb[(size_t)code * DIM + lane];
    float s = v * v;
    #pragma unroll
    for (int off = 32; off > 0; off >>= 1)
        s += __shfl_down(s, off, 64);
    if (lane == 0) esq[code] = s;
}

// -------- kernel B: build the B-fragment stream (validated R3 layout) --------
// 32x32x16 f16 B-frag: lane l holds B[k][n], n = l&31, k = (l>>5)*8 + j.
// Per tile (32 codes): [eh op0..3 | el' op0..3 | cc0[32] = -1024*esq].
__global__ __launch_bounds__(256) void cbprep_kernel(const float* __restrict__ cb,
                                                     const float* __restrict__ esq,
                                                     char* __restrict__ stream) {
    int t    = blockIdx.x * 256 + threadIdx.x;   // 256 tiles * 64 lanes
    int l    = t & 63;
    int tile = t >> 6;                           // global tile 0..255
    char* tbase = stream + (size_t)tile * TILE_BYTES;
    int code = tile * 32 + (l & 31);
    int krow = (l >> 5) * 8;
    #pragma unroll
    for (int o = 0; o < 4; ++o) {
        half8 h, lo;
        split8(cb + (size_t)code * DIM + o * 16 + krow, h, lo);
        *(half8*)(tbase + o * 1024 + l * 16)        = h;
        *(half8*)(tbase + 4096 + o * 1024 + l * 16) = lo;
    }
    if (l < 32)
        *(float*)(tbase + 8192 + l * 4) = -1024.0f * esq[code];
}

// -------- kernel C: MFMA argmin scan, register-double-buffered B stream ------
// One wave per block. Wave owns 32 rows x one chunk (2048 codes, 64 tiles).
#define LOADT(H, L, C, ptr)                                          \
    do {                                                             \
        const char* _tb = (ptr);                                     \
        _Pragma("unroll")                                            \
        for (int _o = 0; _o < 4; ++_o) {                             \
            H[_o] = *(const half8*)(_tb + _o * 1024 + l * 16);       \
            L[_o] = *(const half8*)(_tb + 4096 + _o * 1024 + l * 16);\
        }                                                            \
        C = *(const float*)(_tb + 8192 + m * 4);                     \
    } while (0)

#define COMPUTE(H, L, C, tt)                                                     \
    do {                                                                         \
        floatx16 acc;                                                            \
        _Pragma("unroll")                                                        \
        for (int _i = 0; _i < 16; ++_i) acc[_i] = C;                             \
        _Pragma("unroll")                                                        \
        for (int _o = 0; _o < 4; ++_o) {                                         \
            acc = __builtin_amdgcn_mfma_f32_32x32x16_f16(zhs[_o], H[_o], acc, 0, 0, 0); \
            acc = __builtin_amdgcn_mfma_f32_32x32x16_f16(zl[_o],  H[_o], acc, 0, 0, 0); \
            acc = __builtin_amdgcn_mfma_f32_32x32x16_f16(zh[_o],  L[_o], acc, 0, 0, 0); \
        }                                                                        \
        _Pragma("unroll")                                                        \
        for (int _i = 0; _i < 16; ++_i)                                          \
            if (acc[_i] > best[_i]) { best[_i] = acc[_i]; bt[_i] = (tt); }       \
    } while (0)

__global__ __launch_bounds__(64) void scan_kernel(const float* __restrict__ z,
                                                  const char* __restrict__ stream,
                                                  int* __restrict__ cand_idx) {
    int l     = threadIdx.x;                 // 0..63
    int chunk = blockIdx.x & (NCHUNK - 1);
    int rg    = blockIdx.x >> 2;             // row group 0..1023 (32 rows each)
    int m     = l & 31;                      // A row in tile / B col (code)
    int kg    = l >> 5;

    // A fragments: zh (unscaled), zl = 2048*res, zhs = 2048*zh (exact shift)
    half8 zh[4], zl[4], zhs[4];
    const float* zrow = z + (size_t)(rg * 32 + m) * DIM + kg * 8;
    #pragma unroll
    for (int o = 0; o < 4; ++o) {
        split8(zrow + o * 16, zh[o], zl[o]);
        zhs[o] = zh[o] * (_Float16)2048.0f;
    }

    const char* sbase = stream + (size_t)chunk * CHUNK_BYTES;

    float best[16];
    int   bt[16];
    #pragma unroll
    for (int i = 0; i < 16; ++i) { best[i] = -3.4e38f; bt[i] = 0; }

    // Ping-pong register double buffer: loads for tile t+1 in flight while
    // tile t's MFMAs run. acc = 2048*(dot - esq/2); maximize, tie -> earlier t.
    half8 Ah[4], Al[4], Bh[4], Bl[4];
    float Ac, Bc;
    LOADT(Ah, Al, Ac, sbase);
    for (int t = 0; t < TILES_PER_CHUNK; t += 2) {
        LOADT(Bh, Bl, Bc, sbase + (size_t)(t + 1) * TILE_BYTES);
        COMPUTE(Ah, Al, Ac, t);
        int nt = (t + 2 < TILES_PER_CHUNK) ? t + 2 : TILES_PER_CHUNK - 1;
        LOADT(Ah, Al, Ac, sbase + (size_t)nt * TILE_BYTES);
        COMPUTE(Bh, Bl, Bc, t + 1);
    }

    // Cross-lane argmax over the 32 cols (lane bits 0..4); tie -> lower index.
    #pragma unroll
    for (int i = 0; i < 16; ++i) {
        float v  = best[i];
        int   id = bt[i] * 32 + m;               // code index within chunk
        #pragma unroll
        for (int off = 1; off < 32; off <<= 1) {
            float ov = __shfl_xor(v, off, 64);
            int   oi = __shfl_xor(id, off, 64);
            if (ov > v || (ov == v && oi < id)) { v = ov; id = oi; }
        }
        if (m == 0) {
            int row = rg * 32 + (i & 3) + 8 * (i >> 2) + 4 * kg;
            cand_idx[chunk * N_VOX + row] = chunk * CODES_PER_CHUNK + id;
        }
    }
}

// -------- kernel D: exact fp32 re-score of the 4 chunk winners (validated) ----
__global__ __launch_bounds__(256) void finalize_kernel(const float* __restrict__ z,
                                                       const float* __restrict__ cb,
                                                       const float* __restrict__ esq,
                                                       const int* __restrict__ cand_idx,
                                                       float* __restrict__ out,
                                                       float* __restrict__ partials) {
    int row = blockIdx.x * 256 + threadIdx.x;

    float zr[DIM];
    const float4* zp4 = (const float4*)(z + (size_t)row * DIM);
    #pragma unroll
    for (int d = 0; d < DIM / 4; ++d) {
        float4 t = zp4[d];
        zr[4*d+0] = t.x; zr[4*d+1] = t.y; zr[4*d+2] = t.z; zr[4*d+3] = t.w;
    }

    float best = 3.4e38f;
    int   bidx = 0;
    #pragma unroll
    for (int c = 0; c < NCHUNK; ++c) {   // candidate ids ascend with c
        int id = cand_idx[c * N_VOX + row];
        const float* ep = cb + (size_t)id * DIM;
        float a0 = 0.f, a1 = 0.f, a2 = 0.f, a3 = 0.f;
        #pragma unroll
        for (int d = 0; d < DIM; d += 4) {
            a0 = fmaf(ep[d+0], zr[d+0], a0);
            a1 = fmaf(ep[d+1], zr[d+1], a1);
            a2 = fmaf(ep[d+2], zr[d+2], a2);
            a3 = fmaf(ep[d+3], zr[d+3], a3);
        }
        float dot   = (a0 + a1) + (a2 + a3);
        float score = esq[id] - 2.0f * dot;
        if (score < best) { best = score; bidx = id; }
    }

    out[(size_t)N_VOX * DIM + 2 + row] = (float)bidx;

    const float4* qp = (const float4*)(cb + (size_t)bidx * DIM);
    float4*       op = (float4*)(out + (size_t)row * DIM);

    float ss = 0.f;
    #pragma unroll
    for (int d = 0; d < DIM / 4; ++d) {
        float4 qt = qp[d];
        float zx = zr[4*d+0], zy = zr[4*d+1], zz = zr[4*d+2], zw = zr[4*d+3];
        float dx = qt.x - zx, dy = qt.y - zy, dz = qt.z - zz, dw = qt.w - zw;
        float4 o;
        o.x = zx + dx; o.y = zy + dy; o.z = zz + dz; o.w = zw + dw;
        op[d] = o;
        ss += dx*dx + dy*dy + dz*dz + dw*dw;
    }

    __shared__ float red[256];
    red[threadIdx.x] = ss;
    __syncthreads();
    #pragma unroll
    for (int s = 128; s > 0; s >>= 1) {
        if (threadIdx.x < s) red[threadIdx.x] += red[threadIdx.x + s];
        __syncthreads();
    }
    if (threadIdx.x == 0) partials[blockIdx.x] = red[0];
}

// -------- kernel E: reduce partials -> both losses --------
__global__ __launch_bounds__(128) void loss_kernel(const float* __restrict__ partials,
                                                   float* __restrict__ out) {
    __shared__ float red[128];
    red[threadIdx.x] = partials[threadIdx.x];
    __syncthreads();
    #pragma unroll
    for (int s = 64; s > 0; s >>= 1) {
        if (threadIdx.x < s) red[threadIdx.x] += red[threadIdx.x + s];
        __syncthreads();
    }
    if (threadIdx.x == 0) {
        float mean = red[0] / (float)((size_t)N_VOX * DIM);
        out[(size_t)N_VOX * DIM + 0] = mean;
        out[(size_t)N_VOX * DIM + 1] = mean;
    }
}

extern "C" void kernel_launch(void* const* d_in, const int* in_sizes, int n_in,
                              void* d_out, int out_size, void* d_ws, size_t ws_size,
                              hipStream_t stream) {
    const float* z  = (const float*)d_in[0];   // [32768, 64]
    const float* cb = (const float*)d_in[1];   // [8192, 64]
    float* out = (float*)d_out;

    // ws: stream [256*8320 = 2,129,920 B] | esq [32 KB] | cand_idx [512 KB] | partials
    char*  bstream  = (char*)d_ws;
    float* esq      = (float*)(bstream + (size_t)NTILES * TILE_BYTES);
    int*   cand_idx = (int*)(esq + N_EMB);
    float* partials = (float*)(cand_idx + (size_t)NCHUNK * N_VOX);

    esq_kernel    <<<dim3(N_EMB * 64 / 256), dim3(256), 0, stream>>>(cb, esq);
    cbprep_kernel <<<dim3(NTILES * 64 / 256), dim3(256), 0, stream>>>(cb, esq, bstream);
    scan_kernel   <<<dim3((N_VOX / 32) * NCHUNK), dim3(64), 0, stream>>>(z, bstream, cand_idx);
    finalize_kernel<<<dim3(N_VOX / 256), dim3(256), 0, stream>>>(z, cb, esq, cand_idx, out, partials);
    loss_kernel   <<<1, 128, 0, stream>>>(partials, out);
}

// Round 5
// 208.236 us; speedup vs baseline: 1.0478x; 1.0478x over previous
//
#include <hip/hip_runtime.h>
#include <math.h>

#define N_VOX 32768
#define N_EMB 8192
#define DIM 64
#define NCHUNK 4
#define CODES_PER_CHUNK (N_EMB / NCHUNK)       // 2048
#define TILES_PER_CHUNK (CODES_PER_CHUNK / 32) // 64
#define NTILES (N_EMB / 32)                    // 256
#define TILE_BYTES (4096 + 4096 + 128)         // eh frags | el' frags | cc0[32]
#define CHUNK_BYTES (TILES_PER_CHUNK * TILE_BYTES)
#define NFBLK 512                              // finalize blocks

typedef _Float16 half8 __attribute__((ext_vector_type(8)));
typedef float floatx16 __attribute__((ext_vector_type(16)));

#define FP16_MIN_NORMAL 6.1035156e-5f
#define LO_SCALE 2048.0f

// Split fp32 -> f16 hi (unscaled) + f16 lo = (x - hi)*2048. hi forced to 0 if
// subnormal so lo captures it exactly (dodges MFMA input-denorm ambiguity).
__device__ inline void split8(const float* __restrict__ p, half8& h, half8& l) {
    #pragma unroll
    for (int j = 0; j < 8; ++j) {
        float x  = p[j];
        _Float16 hi = (_Float16)x;
        float hf = (float)hi;
        if (fabsf(hf) < FP16_MIN_NORMAL) { hi = (_Float16)0.f; hf = 0.f; }
        h[j] = hi;
        l[j] = (_Float16)((x - hf) * LO_SCALE);
    }
}

// -------- kernel A: codebook squared norms (validated R1-R4) --------
__global__ __launch_bounds__(256) void esq_kernel(const float* __restrict__ cb,
                                                  float* __restrict__ esq) {
    int gid  = blockIdx.x * blockDim.x + threadIdx.x;
    int code = gid >> 6;
    int lane = threadIdx.x & 63;
    float v = cb[(size_t)code * DIM + lane];
    float s = v * v;
    #pragma unroll
    for (int off = 32; off > 0; off >>= 1)
        s += __shfl_down(s, off, 64);
    if (lane == 0) esq[code] = s;
}

// -------- kernel B: build the B-fragment stream (validated R3/R4 layout) ------
// 32x32x16 f16 B-frag: lane l holds B[k][n], n = l&31, k = (l>>5)*8 + j.
// Per tile (32 codes): [eh op0..3 | el' op0..3 | cc0[32] = -1024*esq].
__global__ __launch_bounds__(256) void cbprep_kernel(const float* __restrict__ cb,
                                                     const float* __restrict__ esq,
                                                     char* __restrict__ stream) {
    int t    = blockIdx.x * 256 + threadIdx.x;   // 256 tiles * 64 lanes
    int l    = t & 63;
    int tile = t >> 6;                           // global tile 0..255
    char* tbase = stream + (size_t)tile * TILE_BYTES;
    int code = tile * 32 + (l & 31);
    int krow = (l >> 5) * 8;
    #pragma unroll
    for (int o = 0; o < 4; ++o) {
        half8 h, lo;
        split8(cb + (size_t)code * DIM + o * 16 + krow, h, lo);
        *(half8*)(tbase + o * 1024 + l * 16)        = h;
        *(half8*)(tbase + 4096 + o * 1024 + l * 16) = lo;
    }
    if (l < 32)
        *(float*)(tbase + 8192 + l * 4) = -1024.0f * esq[code];
}

// -------- kernel C: MFMA argmin scan ----------------------------------------
// Block = 4 waves, all on the same chunk (shared tile stream -> L1 reuse).
// Wave owns 64 rows (2 row-tiles of 32) x one chunk (2048 codes, 64 tiles).
// acc = 2048*(dot - esq/2); maximize, tie -> earlier tile. Math identical R3/R4.
__global__ __launch_bounds__(256) void scan_kernel(const float* __restrict__ z,
                                                   const char* __restrict__ stream,
                                                   int* __restrict__ cand_idx) {
    int tid   = threadIdx.x;
    int l     = tid & 63;
    int w     = tid >> 6;                        // wave 0..3
    int chunk = blockIdx.x & (NCHUNK - 1);
    int bg    = blockIdx.x >> 2;                 // 0..127, 256 rows per block
    int m     = l & 31;                          // A row in tile / B col (code)
    int kg    = l >> 5;
    int rowBase = bg * 256 + w * 64;             // wave's 64 rows

    // A fragments: zh (unscaled), zl = 2048*res, zhs = 2048*zh (exact shift)
    half8 zh[2][4], zl[2][4], zhs[2][4];
    #pragma unroll
    for (int rt = 0; rt < 2; ++rt) {
        const float* zrow = z + (size_t)(rowBase + rt * 32 + m) * DIM + kg * 8;
        #pragma unroll
        for (int o = 0; o < 4; ++o) {
            split8(zrow + o * 16, zh[rt][o], zl[rt][o]);
            zhs[rt][o] = zh[rt][o] * (_Float16)2048.0f;
        }
    }

    const char* sbase = stream + (size_t)chunk * CHUNK_BYTES;

    float best[2][16];
    int   bt[2][16];
    #pragma unroll
    for (int rt = 0; rt < 2; ++rt)
        #pragma unroll
        for (int i = 0; i < 16; ++i) { best[rt][i] = -3.4e38f; bt[rt][i] = 0; }

    for (int t = 0; t < TILES_PER_CHUNK; ++t) {
        const char* tb = sbase + (size_t)t * TILE_BYTES;
        half8 bh[4], bl[4];
        #pragma unroll
        for (int o = 0; o < 4; ++o) {
            bh[o] = *(const half8*)(tb + o * 1024 + l * 16);
            bl[o] = *(const half8*)(tb + 4096 + o * 1024 + l * 16);
        }
        float c0 = *(const float*)(tb + 8192 + m * 4);   // -1024*esq[code]

        #pragma unroll
        for (int rt = 0; rt < 2; ++rt) {
            floatx16 acc;
            #pragma unroll
            for (int i = 0; i < 16; ++i) acc[i] = c0;
            #pragma unroll
            for (int o = 0; o < 4; ++o) {
                acc = __builtin_amdgcn_mfma_f32_32x32x16_f16(zhs[rt][o], bh[o], acc, 0, 0, 0);
                acc = __builtin_amdgcn_mfma_f32_32x32x16_f16(zl[rt][o],  bh[o], acc, 0, 0, 0);
                acc = __builtin_amdgcn_mfma_f32_32x32x16_f16(zh[rt][o],  bl[o], acc, 0, 0, 0);
            }
            #pragma unroll
            for (int i = 0; i < 16; ++i)
                if (acc[i] > best[rt][i]) { best[rt][i] = acc[i]; bt[rt][i] = t; }
        }
    }

    // Cross-lane argmax over the 32 cols (lane bits 0..4); tie -> lower index.
    #pragma unroll
    for (int rt = 0; rt < 2; ++rt) {
        #pragma unroll
        for (int i = 0; i < 16; ++i) {
            float v  = best[rt][i];
            int   id = bt[rt][i] * 32 + m;           // code index within chunk
            #pragma unroll
            for (int off = 1; off < 32; off <<= 1) {
                float ov = __shfl_xor(v, off, 64);
                int   oi = __shfl_xor(id, off, 64);
                if (ov > v || (ov == v && oi < id)) { v = ov; id = oi; }
            }
            if (m == 0) {
                int row = rowBase + rt * 32 + (i & 3) + 8 * (i >> 2) + 4 * kg;
                cand_idx[chunk * N_VOX + row] = chunk * CODES_PER_CHUNK + id;
            }
        }
    }
}

// -------- kernel D: exact fp32 re-score, thread per (row, candidate) ---------
// 4 lanes per row; validated fp32 dot chain; min over 4 lanes via shfl (width 4,
// tie -> lower id == first-occurrence, matching the validated sequential loop).
__global__ __launch_bounds__(256) void finalize_kernel(const float* __restrict__ z,
                                                       const float* __restrict__ cb,
                                                       const float* __restrict__ esq,
                                                       const int* __restrict__ cand_idx,
                                                       float* __restrict__ out,
                                                       float* __restrict__ partials) {
    int g    = blockIdx.x * 256 + threadIdx.x;
    int row  = g >> 2;
    int cand = g & 3;

    float zr[DIM];
    const float4* zp4 = (const float4*)(z + (size_t)row * DIM);
    #pragma unroll
    for (int d = 0; d < DIM / 4; ++d) {
        float4 t = zp4[d];
        zr[4*d+0] = t.x; zr[4*d+1] = t.y; zr[4*d+2] = t.z; zr[4*d+3] = t.w;
    }

    int id = cand_idx[cand * N_VOX + row];
    const float* ep = cb + (size_t)id * DIM;
    float a0 = 0.f, a1 = 0.f, a2 = 0.f, a3 = 0.f;
    #pragma unroll
    for (int d = 0; d < DIM; d += 4) {   // identical 4-chain to validated R1-R4
        a0 = fmaf(ep[d+0], zr[d+0], a0);
        a1 = fmaf(ep[d+1], zr[d+1], a1);
        a2 = fmaf(ep[d+2], zr[d+2], a2);
        a3 = fmaf(ep[d+3], zr[d+3], a3);
    }
    float dot   = (a0 + a1) + (a2 + a3);
    float score = esq[id] - 2.0f * dot;

    #pragma unroll
    for (int off = 1; off < 4; off <<= 1) {
        float ov = __shfl_xor(score, off, 4);
        int   oi = __shfl_xor(id, off, 4);
        if (ov < score || (ov == score && oi < id)) { score = ov; id = oi; }
    }
    // all 4 lanes now hold the winning id for this row

    if (cand == 0)
        out[(size_t)N_VOX * DIM + 2 + row] = (float)id;

    // cooperative gather+write: lane handles elements [cand*16, cand*16+16)
    const float4* qp = (const float4*)(cb + (size_t)id * DIM + cand * 16);
    float4*       op = (float4*)(out + (size_t)row * DIM + cand * 16);
    float ss = 0.f;
    #pragma unroll
    for (int d = 0; d < 4; ++d) {
        float4 qt = qp[d];
        int b = cand * 16 + 4 * d;
        float zx = zr[b+0], zy = zr[b+1], zz = zr[b+2], zw = zr[b+3];
        float dx = qt.x - zx, dy = qt.y - zy, dz = qt.z - zz, dw = qt.w - zw;
        float4 o;
        o.x = zx + dx; o.y = zy + dy; o.z = zz + dz; o.w = zw + dw;
        op[d] = o;
        ss += dx*dx + dy*dy + dz*dz + dw*dw;
    }

    __shared__ float red[256];
    red[threadIdx.x] = ss;
    __syncthreads();
    #pragma unroll
    for (int s = 128; s > 0; s >>= 1) {
        if (threadIdx.x < s) red[threadIdx.x] += red[threadIdx.x + s];
        __syncthreads();
    }
    if (threadIdx.x == 0) partials[blockIdx.x] = red[0];
}

// -------- kernel E: reduce 512 partials -> both losses --------
__global__ __launch_bounds__(256) void loss_kernel(const float* __restrict__ partials,
                                                   float* __restrict__ out) {
    __shared__ float red[256];
    red[threadIdx.x] = partials[threadIdx.x] + partials[threadIdx.x + 256];
    __syncthreads();
    #pragma unroll
    for (int s = 128; s > 0; s >>= 1) {
        if (threadIdx.x < s) red[threadIdx.x] += red[threadIdx.x + s];
        __syncthreads();
    }
    if (threadIdx.x == 0) {
        float mean = red[0] / (float)((size_t)N_VOX * DIM);
        out[(size_t)N_VOX * DIM + 0] = mean;
        out[(size_t)N_VOX * DIM + 1] = mean;
    }
}

extern "C" void kernel_launch(void* const* d_in, const int* in_sizes, int n_in,
                              void* d_out, int out_size, void* d_ws, size_t ws_size,
                              hipStream_t stream) {
    const float* z  = (const float*)d_in[0];   // [32768, 64]
    const float* cb = (const float*)d_in[1];   // [8192, 64]
    float* out = (float*)d_out;

    // ws: stream [256*8320 = 2,129,920 B] | esq [32 KB] | cand_idx [512 KB] | partials
    char*  bstream  = (char*)d_ws;
    float* esq      = (float*)(bstream + (size_t)NTILES * TILE_BYTES);
    int*   cand_idx = (int*)(esq + N_EMB);
    float* partials = (float*)(cand_idx + (size_t)NCHUNK * N_VOX);

    esq_kernel    <<<dim3(N_EMB * 64 / 256), dim3(256), 0, stream>>>(cb, esq);
    cbprep_kernel <<<dim3(NTILES * 64 / 256), dim3(256), 0, stream>>>(cb, esq, bstream);
    scan_kernel   <<<dim3((N_VOX / 256) * NCHUNK), dim3(256), 0, stream>>>(z, bstream, cand_idx);
    finalize_kernel<<<dim3(NFBLK), dim3(256), 0, stream>>>(z, cb, esq, cand_idx, out, partials);
    loss_kernel   <<<1, 256, 0, stream>>>(partials, out);
}